// Round 18
// baseline (87.207 us; speedup 1.0000x reference)
//
#include <hip/hip_runtime.h>
#include <hip/hip_bf16.h>
#include <cstdint>

#define B_SZ 2048
#define T_SZ 512
#define F_SZ 64
#define BPB  2              // batch rows per block
#define TCH  64             // timesteps per chunk
#define NCHK (T_SZ / TCH)   // 8
#define NBLK (B_SZ / BPB)   // 1024
#define NTHR 256            // wv0 scan, wv1 MFMA, wv2-3 staging
#define ROWS (BPB * TCH)    // 128 rows (b,t) per chunk  (same as R17)
#define MT   (ROWS / 16)    // 8 M-tiles
#define NPC  (ROWS * 16)    // 2048 float4 staging pieces per chunk
#define NSTG 128            // staging threads (wv2+wv3)
#define PPT  (NPC / NSTG)   // 16 pieces per staging thread
#define TSTR 44             // zbuf t-stride (floats): 2 elems x 20 + pad
#define ESTR 20             // zbuf b-elem stride (floats)

#define L2E 1.4426950408889634f

typedef __attribute__((ext_vector_type(8))) short short8;
typedef __attribute__((ext_vector_type(4))) float f32x4;

__device__ __forceinline__ float fast_rcp(float x) { return __builtin_amdgcn_rcpf(x); }
__device__ __forceinline__ float exp2h(float x)    { return __builtin_amdgcn_exp2f(x); }
__device__ __forceinline__ float sigm_s(float zs)  { return fast_rcp(1.0f + exp2h(zs)); }
__device__ __forceinline__ float sigm_n(float x)   { return sigm_s(x * (-L2E)); }

__device__ __forceinline__ unsigned short f2bf(float f) {
    __hip_bfloat16 h = (__hip_bfloat16)f;   // RNE
    return *reinterpret_cast<unsigned short*>(&h);
}

template<int CTRL>
__device__ __forceinline__ float dppmv(float v) {
    return __int_as_float(__builtin_amdgcn_mov_dpp(__float_as_int(v), CTRL, 0xF, 0xF, true));
}
// row_shr:N -> lane i reads lane i-N
#define DPP_SHR6 0x116   // i-gates: src lanes 0..2 -> dst 6..8
#define DPP_SHR3 0x113   // f-gates: src lanes 3..5 -> dst 6..8
#define DPP_SHL3 0x103   // o-gates: src lanes 9..11 -> dst 6..8
// row_newbcast:N (0x150+N): broadcast row-lane N to all 16 lanes (VALU DPP)
#define DPP_NB6  0x156
#define DPP_NB7  0x157
#define DPP_NB8  0x158

__global__ __launch_bounds__(NTHR) void lstm_mfma(const float* __restrict__ x,
                                                  const float* __restrict__ W,
                                                  const float* __restrict__ U,
                                                  const float* __restrict__ bias,
                                                  const float* __restrict__ Wd,
                                                  const float* __restrict__ bdp,
                                                  float* __restrict__ out) {
    // A-fragment-ordered x (bf16): per (Mtile,Ktile): 64 lanes x 16B
    __shared__ unsigned int xfrag[2][MT * 2 * 256];   // 2 x 16 KB
    __shared__ float zbuf[2][TCH * TSTR];             // 2 x 11 KB

    const int tid = threadIdx.x;
    const int wv  = tid >> 6;
    const int ln  = tid & 63;
    const int b0  = blockIdx.x * BPB;

    // ---- gate mapping: MFMA col n = Keras gate col (q*3+m), q=n/3, m=n%3 ----
    const int n  = ln & 15;                 // 12 real gates + 4 pad
    const int q  = n / 3;                   // 0:i 1:f 2:g 3:o (n<12)
    const float scq = (q == 2) ? (-2.0f * L2E) : (-L2E);

    // ---- B-fragments: W stationary in VGPRs (wv1 only uses them) ----
    short8 bfrag[2];
    #pragma unroll
    for (int kt = 0; kt < 2; ++kt) {
        short8 s;
        #pragma unroll
        for (int e = 0; e < 8; ++e) {
            const int hh = e >> 2, j = e & 3;
            const int kk = kt * 32 + hh * 16 + 4 * (ln >> 4) + j;   // f index
            const float w = (n < 12 && wv == 1) ? W[kk * 12 + n] * scq : 0.0f;
            s[e] = (short)f2bf(w);
        }
        bfrag[kt] = s;
    }
    const float bias_s = (n < 12) ? bias[n] * scq : 0.0f;

    // ---- scan constants (wv0): lane n = gate col; elem e16 in lanes 0..31 ----
    const int e16 = (ln >> 4) & 1;          // batch elem 0..1 (lanes 32-63 mirror)
    float u0 = 0.f, u1 = 0.f, u2 = 0.f, gA = 0.f, gB = 0.f;
    if (n < 12) {
        u0 = U[0 * 12 + n] * scq;
        u1 = U[1 * 12 + n] * scq;
        u2 = U[2 * 12 + n] * scq;
        if (q == 2) { gA = -4.0f * L2E; gB = 2.0f * L2E; }  // pre-scaled tanh
        else        { gA = 1.0f;        gB = 0.0f;       }  // sigmoid
    }
    // state: cs = -2*L2E*c (g-lanes 6..8); h broadcasts h0b/h1b/h2b
    float cs = 0.f, h0b = 0.f, h1b = 0.f, h2b = 0.f;

    auto comp = [&](float z4) {
        const float z  = fmaf(h0b, u0, fmaf(h1b, u1, fmaf(h2b, u2, z4)));
        const float r  = fast_rcp(1.0f + exp2h(z));      // ONE exp2+rcp for all gates
        const float gt = fmaf(gA, r, gB);                // sigmoid / pre-scaled tanh
        const float iV = dppmv<DPP_SHR6>(gt);            // i -> g-lanes
        const float fV = dppmv<DPP_SHR3>(gt);            // f -> g-lanes
        const float oV = dppmv<DPP_SHL3>(gt);            // o -> g-lanes
        cs = fmaf(fV, cs, iV * gt);                      // g-lanes: gt = -2*L2E*g
        const float th = fmaf(2.0f, fast_rcp(1.0f + exp2h(cs)), -1.0f);  // tanh(c)
        const float h  = oV * th;                        // h_m on lane 6+m
        h0b = dppmv<DPP_NB6>(h);                         // VALU row-broadcasts
        h1b = dppmv<DPP_NB7>(h);
        h2b = dppmv<DPP_NB8>(h);
    };

    auto scan_chunk = [&](const float* zb) {
        const float* zp = zb + e16 * ESTR + n;
        float pf[8];
        #pragma unroll
        for (int i = 0; i < 8; ++i) pf[i] = zp[i * TSTR];
        __builtin_amdgcn_s_setprio(1);
        #pragma unroll
        for (int tt = 0; tt < TCH; ++tt) {               // static unroll -> pf in regs
            const float z4 = pf[tt & 7];
            if (tt + 8 < TCH) pf[tt & 7] = zp[(tt + 8) * TSTR];
            comp(z4);
        }
        __builtin_amdgcn_s_setprio(0);
    };

    // ---- staging (wv2-3 only): issue-early global loads, convert+write bf16 A-frags ----
    float4 v[PPT];
    const int stid = tid - 128;             // 0..127 for wv2-3
    auto stage_issue = [&](int ck) {
        const int t0 = ck * TCH;
        #pragma unroll
        for (int i = 0; i < PPT; ++i) {
            const int piece = i * NSTG + stid;
            const int row = piece >> 4, g = piece & 15;  // row = b*64 + t
            v[i] = *reinterpret_cast<const float4*>(
                x + ((size_t)(b0 + (row >> 6)) * T_SZ + (t0 + (row & 63))) * F_SZ + (g << 2));
        }
    };
    auto stage_write = [&](int buf) {
        #pragma unroll
        for (int i = 0; i < PPT; ++i) {
            const int piece = i * NSTG + stid;
            const int row = piece >> 4, g = piece & 15;
            const int u_off = ((row >> 4) * 2 + (g >> 3)) * 256
                            + (((row & 15) | ((g & 3) << 4)) << 2) + ((g >> 2) & 1) * 2;
            uint2 pk;
            pk.x = (unsigned)f2bf(v[i].x) | ((unsigned)f2bf(v[i].y) << 16);
            pk.y = (unsigned)f2bf(v[i].z) | ((unsigned)f2bf(v[i].w) << 16);
            *reinterpret_cast<uint2*>(&xfrag[buf][u_off]) = pk;
        }
    };

    auto mfma_chunk = [&](int cur) {
        #pragma unroll
        for (int mt = 0; mt < MT; ++mt) {
            f32x4 acc = { bias_s, bias_s, bias_s, bias_s };
            const short8 a0 = *reinterpret_cast<const short8*>(&xfrag[cur][(mt * 2 + 0) * 256 + (ln << 2)]);
            const short8 a1 = *reinterpret_cast<const short8*>(&xfrag[cur][(mt * 2 + 1) * 256 + (ln << 2)]);
            acc = __builtin_amdgcn_mfma_f32_16x16x32_bf16(a0, bfrag[0], acc, 0, 0, 0);
            acc = __builtin_amdgcn_mfma_f32_16x16x32_bf16(a1, bfrag[1], acc, 0, 0, 0);
            const int rbase = mt * 16 + 4 * (ln >> 4);
            #pragma unroll
            for (int r = 0; r < 4; ++r) {
                const int rr = rbase + r;                 // row = b*64 + t
                zbuf[cur][(rr & 63) * TSTR + (rr >> 6) * ESTR + n] = acc[r];
            }
        }
    };

    // ---- prologue: staging waves fill chunk 0 ----
    if (wv >= 2) { stage_issue(0); stage_write(0); }
    __syncthreads();

    // ---- pipeline: staging(k+1) || mfma z(k) || scan(k-1), one barrier/chunk ----
    for (int k = 0; k < NCHK; ++k) {
        const int cur = k & 1;
        if (wv >= 2) {
            if (k + 1 < NCHK) { stage_issue(k + 1); stage_write(cur ^ 1); }
        } else if (wv == 1) {
            mfma_chunk(cur);
        } else if (k > 0) {
            scan_chunk(zbuf[cur ^ 1]);
        }
        __syncthreads();
    }

    // ---- epilogue: scan last chunk + dense head ----
    if (wv == 0) {
        scan_chunk(zbuf[(NCHK - 1) & 1]);
        if (n == 0 && ln < 32) {   // lanes 0 and 16: elems 0,1
            const float h0 = h0b, h1 = h1b, h2 = h2b;
            const float logit = bdp[0] + h0 * Wd[0] + h1 * Wd[1] + h2 * Wd[2];
            out[b0 + e16] = sigm_n(logit);
        }
    }
}

extern "C" void kernel_launch(void* const* d_in, const int* in_sizes, int n_in,
                              void* d_out, int out_size, void* d_ws, size_t ws_size,
                              hipStream_t stream) {
    (void)in_sizes; (void)n_in; (void)out_size; (void)d_ws; (void)ws_size;
    const float* x  = (const float*)d_in[0];
    const float* W  = (const float*)d_in[1];
    const float* U  = (const float*)d_in[2];
    const float* b  = (const float*)d_in[3];
    const float* Wd = (const float*)d_in[4];
    const float* bd = (const float*)d_in[5];
    float* out = (float*)d_out;

    lstm_mfma<<<NBLK, NTHR, 0, stream>>>(x, W, U, b, Wd, bd, out);
}

// Round 19
// 67.051 us; speedup vs baseline: 1.3006x; 1.3006x over previous
//
#include <hip/hip_runtime.h>
#include <hip/hip_bf16.h>
#include <cstdint>

#define B_SZ 2048
#define T_SZ 512
#define F_SZ 64
#define BPB  4              // batch rows per block
#define TCH  32             // timesteps per staging/MFMA period
#define NCHK (T_SZ / TCH)   // 16 periods
#define NBLK (B_SZ / BPB)   // 512 -> 2 blocks/CU (LDS ~76KB)
#define NTHR 256            // wv0 scan, wv1 MFMA, wv2-3 staging
#define ROWS (BPB * TCH)    // 128 rows (b,t) per period
#define MT   (ROWS / 16)    // 8 M-tiles
#define NPC  (ROWS * 16)    // 2048 float4 staging pieces per period
#define NSTG 128            // staging threads (wv2+wv3)
#define PPT  (NPC / NSTG)   // 16 pieces per staging thread
#define TSTR 84             // zbuf t-stride (floats)
#define ESTR 20             // zbuf b-elem stride (floats)

#define L2E 1.4426950408889634f

typedef __attribute__((ext_vector_type(8))) short short8;
typedef __attribute__((ext_vector_type(4))) float f32x4;

__device__ __forceinline__ float fast_rcp(float x) { return __builtin_amdgcn_rcpf(x); }
__device__ __forceinline__ float exp2h(float x)    { return __builtin_amdgcn_exp2f(x); }
__device__ __forceinline__ float sigm_s(float zs)  { return fast_rcp(1.0f + exp2h(zs)); }
__device__ __forceinline__ float sigm_n(float x)   { return sigm_s(x * (-L2E)); }

__device__ __forceinline__ unsigned short f2bf(float f) {
    __hip_bfloat16 h = (__hip_bfloat16)f;   // RNE
    return *reinterpret_cast<unsigned short*>(&h);
}

template<int CTRL>
__device__ __forceinline__ float dppmv(float v) {
    return __int_as_float(__builtin_amdgcn_mov_dpp(__float_as_int(v), CTRL, 0xF, 0xF, true));
}
// row_shr:N -> lane i reads lane i-N ; row_shl:N -> lane i reads lane i+N
#define DPP_SHR6 0x116   // i-gates: src lanes 0..2 -> dst 6..8
#define DPP_SHR3 0x113   // f-gates: src lanes 3..5 -> dst 6..8
#define DPP_SHL3 0x103   // o-gates: src lanes 9..11 -> dst 6..8
// row_newbcast:N (0x150+N): broadcast row-lane N to all 16 lanes (VALU DPP)
#define DPP_NB6  0x156
#define DPP_NB7  0x157
#define DPP_NB8  0x158

__global__ __launch_bounds__(NTHR) void lstm_mfma(const float* __restrict__ x,
                                                  const float* __restrict__ W,
                                                  const float* __restrict__ U,
                                                  const float* __restrict__ bias,
                                                  const float* __restrict__ Wd,
                                                  const float* __restrict__ bdp,
                                                  float* __restrict__ out) {
    // A-fragment-ordered x (bf16), double-buffered per period
    __shared__ unsigned int xfrag[2][MT * 2 * 256];   // 2 x 16 KB
    // z ring: 4 quarters x 32 t-rows = 128 rows (scan consumes 2 quarters per run)
    __shared__ float zbuf[4 * TCH * TSTR];            // 43 KB

    const int tid = threadIdx.x;
    const int wv  = tid >> 6;
    const int ln  = tid & 63;
    const int b0  = blockIdx.x * BPB;

    // ---- gate mapping: MFMA col n = Keras gate col (q*3+m), q=n/3, m=n%3 ----
    const int n  = ln & 15;                 // 12 real gates + 4 pad
    const int q  = n / 3;                   // 0:i 1:f 2:g 3:o (n<12)
    const float scq = (q == 2) ? (-2.0f * L2E) : (-L2E);

    // ---- B-fragments: W stationary in VGPRs (wv1 only uses them) ----
    short8 bfrag[2];
    #pragma unroll
    for (int kt = 0; kt < 2; ++kt) {
        short8 s;
        #pragma unroll
        for (int e = 0; e < 8; ++e) {
            const int hh = e >> 2, j = e & 3;
            const int kk = kt * 32 + hh * 16 + 4 * (ln >> 4) + j;   // f index
            const float w = (n < 12 && wv == 1) ? W[kk * 12 + n] * scq : 0.0f;
            s[e] = (short)f2bf(w);
        }
        bfrag[kt] = s;
    }
    const float bias_s = (n < 12) ? bias[n] * scq : 0.0f;

    // ---- scan constants (wv0): lane n = gate col; elem e16 = ln>>4 (0..3) ----
    const int e16 = ln >> 4;
    float u0 = 0.f, u1 = 0.f, u2 = 0.f, gA = 0.f, gB = 0.f;
    if (n < 12) {
        u0 = U[0 * 12 + n] * scq;
        u1 = U[1 * 12 + n] * scq;
        u2 = U[2 * 12 + n] * scq;
        if (q == 2) { gA = -4.0f * L2E; gB = 2.0f * L2E; }  // pre-scaled tanh
        else        { gA = 1.0f;        gB = 0.0f;       }  // sigmoid
    }
    // state: cs = -2*L2E*c (g-lanes 6..8); h broadcasts h0b/h1b/h2b
    float cs = 0.f, h0b = 0.f, h1b = 0.f, h2b = 0.f;

    auto comp = [&](float z4) {
        const float z  = fmaf(h0b, u0, fmaf(h1b, u1, fmaf(h2b, u2, z4)));
        const float r  = fast_rcp(1.0f + exp2h(z));      // ONE exp2+rcp for all gates
        const float gt = fmaf(gA, r, gB);                // sigmoid / pre-scaled tanh
        const float iV = dppmv<DPP_SHR6>(gt);            // i -> g-lanes
        const float fV = dppmv<DPP_SHR3>(gt);            // f -> g-lanes
        const float oV = dppmv<DPP_SHL3>(gt);            // o -> g-lanes
        cs = fmaf(fV, cs, iV * gt);                      // g-lanes: gt = -2*L2E*g
        const float th = fmaf(2.0f, fast_rcp(1.0f + exp2h(cs)), -1.0f);  // tanh(c)
        const float h  = oV * th;                        // h_m on lane 6+m
        h0b = dppmv<DPP_NB6>(h);                         // VALU row-broadcasts
        h1b = dppmv<DPP_NB7>(h);
        h2b = dppmv<DPP_NB8>(h);
    };

    // 64-step scan over two consecutive quarters starting at t-row base_row
    auto scan64 = [&](int base_row) {
        const float* zp = zbuf + (size_t)base_row * TSTR + e16 * ESTR + n;
        float pf[8];
        #pragma unroll
        for (int i = 0; i < 8; ++i) pf[i] = zp[i * TSTR];
        __builtin_amdgcn_s_setprio(1);
        #pragma unroll
        for (int tt = 0; tt < 2 * TCH; ++tt) {           // 64 steps, static pf indices
            const float z4 = pf[tt & 7];
            if (tt + 8 < 2 * TCH) pf[tt & 7] = zp[(tt + 8) * TSTR];
            comp(z4);
        }
        __builtin_amdgcn_s_setprio(0);
    };

    // ---- staging (wv2-3 only): issue-early global loads, convert+write bf16 A-frags ----
    float4 v[PPT];
    const int stid = tid - 128;             // 0..127 for wv2-3
    auto stage_issue = [&](int ck) {
        const int t0 = ck * TCH;
        #pragma unroll
        for (int i = 0; i < PPT; ++i) {
            const int piece = i * NSTG + stid;
            const int row = piece >> 4, g = piece & 15;  // row = b*32 + t
            v[i] = *reinterpret_cast<const float4*>(
                x + ((size_t)(b0 + (row >> 5)) * T_SZ + (t0 + (row & 31))) * F_SZ + (g << 2));
        }
    };
    auto stage_write = [&](int buf) {
        #pragma unroll
        for (int i = 0; i < PPT; ++i) {
            const int piece = i * NSTG + stid;
            const int row = piece >> 4, g = piece & 15;
            const int u_off = ((row >> 4) * 2 + (g >> 3)) * 256
                            + (((row & 15) | ((g & 3) << 4)) << 2) + ((g >> 2) & 1) * 2;
            uint2 pk;
            pk.x = (unsigned)f2bf(v[i].x) | ((unsigned)f2bf(v[i].y) << 16);
            pk.y = (unsigned)f2bf(v[i].z) | ((unsigned)f2bf(v[i].w) << 16);
            *reinterpret_cast<uint2*>(&xfrag[buf][u_off]) = pk;
        }
    };

    auto mfma_period = [&](int p) {
        const int buf  = p & 1;
        const int qoff = (p & 3) * TCH;                  // ring quarter base row
        #pragma unroll
        for (int mt = 0; mt < MT; ++mt) {
            f32x4 acc = { bias_s, bias_s, bias_s, bias_s };
            const short8 a0 = *reinterpret_cast<const short8*>(&xfrag[buf][(mt * 2 + 0) * 256 + (ln << 2)]);
            const short8 a1 = *reinterpret_cast<const short8*>(&xfrag[buf][(mt * 2 + 1) * 256 + (ln << 2)]);
            acc = __builtin_amdgcn_mfma_f32_16x16x32_bf16(a0, bfrag[0], acc, 0, 0, 0);
            acc = __builtin_amdgcn_mfma_f32_16x16x32_bf16(a1, bfrag[1], acc, 0, 0, 0);
            const int rbase = mt * 16 + 4 * (ln >> 4);
            #pragma unroll
            for (int r = 0; r < 4; ++r) {
                const int rr = rbase + r;                 // row = b*32 + t
                zbuf[(size_t)(qoff + (rr & 31)) * TSTR + (rr >> 5) * ESTR + n] = acc[r];
            }
        }
    };

    // ---- prologue: staging waves fill period 0 ----
    if (wv >= 2) { stage_issue(0); stage_write(0); }
    __syncthreads();

    // ---- pipeline: staging(p+1) || mfma z(p) || scan64 on even p (quarters p-2,p-1) ----
    for (int p = 0; p < NCHK; ++p) {
        if (wv >= 2) {
            if (p + 1 < NCHK) { stage_issue(p + 1); stage_write((p + 1) & 1); }
        } else if (wv == 1) {
            mfma_period(p);
        } else if (p >= 2 && (p & 1) == 0) {
            scan64(((p - 2) & 3) * TCH);                  // rows 0..63 or 64..127
        }
        __syncthreads();
    }

    // ---- epilogue: scan periods 14,15 (quarters 2,3 = rows 64..127) + dense head ----
    if (wv == 0) {
        scan64(2 * TCH);
        if (n == 0) {   // lanes 0,16,32,48: elems 0..3
            const float logit = bdp[0] + h0b * Wd[0] + h1b * Wd[1] + h2b * Wd[2];
            out[b0 + e16] = sigm_n(logit);
        }
    }
}

extern "C" void kernel_launch(void* const* d_in, const int* in_sizes, int n_in,
                              void* d_out, int out_size, void* d_ws, size_t ws_size,
                              hipStream_t stream) {
    (void)in_sizes; (void)n_in; (void)out_size; (void)d_ws; (void)ws_size;
    const float* x  = (const float*)d_in[0];
    const float* W  = (const float*)d_in[1];
    const float* U  = (const float*)d_in[2];
    const float* b  = (const float*)d_in[3];
    const float* Wd = (const float*)d_in[4];
    const float* bd = (const float*)d_in[5];
    float* out = (float*)d_out;

    lstm_mfma<<<NBLK, NTHR, 0, stream>>>(x, W, U, b, Wd, bd, out);
}

// Round 20
// 56.694 us; speedup vs baseline: 1.5382x; 1.1827x over previous
//
#include <hip/hip_runtime.h>
#include <hip/hip_bf16.h>
#include <cstdint>

#define B_SZ 2048
#define T_SZ 512
#define F_SZ 64
#define BPB  4              // batch rows per block
#define TCH  32             // timesteps per period
#define NCHK (T_SZ / TCH)   // 16 periods
#define NBLK (B_SZ / BPB)   // 512 -> 2 blocks/CU (LDS ~76KB)
#define NTHR 256            // wv0 scan, wv1 MFMA, wv2-3 staging
#define ROWS (BPB * TCH)    // 128 rows (b,t) per period
#define MT   (ROWS / 16)    // 8 M-tiles
#define NPC  (ROWS * 16)    // 2048 float4 staging pieces per period
#define NSTG 128            // staging threads (wv2+wv3)
#define PPT  (NPC / NSTG)   // 16 pieces per staging thread
#define TSTR 84             // zbuf t-stride (floats)
#define ESTR 20             // zbuf b-elem stride (floats)

#define L2E 1.4426950408889634f

typedef __attribute__((ext_vector_type(8))) short short8;
typedef __attribute__((ext_vector_type(4))) float f32x4;

__device__ __forceinline__ float fast_rcp(float x) { return __builtin_amdgcn_rcpf(x); }
__device__ __forceinline__ float exp2h(float x)    { return __builtin_amdgcn_exp2f(x); }
__device__ __forceinline__ float sigm_s(float zs)  { return fast_rcp(1.0f + exp2h(zs)); }
__device__ __forceinline__ float sigm_n(float x)   { return sigm_s(x * (-L2E)); }

__device__ __forceinline__ unsigned short f2bf(float f) {
    __hip_bfloat16 h = (__hip_bfloat16)f;   // RNE
    return *reinterpret_cast<unsigned short*>(&h);
}

template<int CTRL>
__device__ __forceinline__ float dppmv(float v) {
    return __int_as_float(__builtin_amdgcn_mov_dpp(__float_as_int(v), CTRL, 0xF, 0xF, true));
}
// row_shr:N -> lane i reads lane i-N ; row_shl:N -> lane i reads lane i+N
#define DPP_SHR6 0x116   // i-gates: src lanes 0..2 -> dst 6..8
#define DPP_SHR3 0x113   // f-gates: src lanes 3..5 -> dst 6..8
#define DPP_SHL3 0x103   // o-gates: src lanes 9..11 -> dst 6..8
// row_newbcast:N (0x150+N): broadcast row-lane N to all 16 lanes (VALU DPP)
#define DPP_NB6  0x156
#define DPP_NB7  0x157
#define DPP_NB8  0x158

// ---- LDS flag protocol: writer (data -> lgkmcnt(0) -> flag), reader (spin -> lgkmcnt(0)) ----
__device__ __forceinline__ void wait_flag(volatile int* f) {
    if (!*f) {
        while (!*f) __builtin_amdgcn_s_sleep(8);   // back off: don't contend DS pipe
    }
    asm volatile("s_waitcnt lgkmcnt(0)" ::: "memory");   // acquire + compiler fence
}
__device__ __forceinline__ void set_flag(volatile int* f) {
    asm volatile("s_waitcnt lgkmcnt(0)" ::: "memory");   // release: prior LDS writes visible
    *f = 1;
}

__global__ __launch_bounds__(NTHR) void lstm_mfma(const float* __restrict__ x,
                                                  const float* __restrict__ W,
                                                  const float* __restrict__ U,
                                                  const float* __restrict__ bias,
                                                  const float* __restrict__ Wd,
                                                  const float* __restrict__ bdp,
                                                  float* __restrict__ out) {
    // A-fragment-ordered x (bf16), ring-2 by period
    __shared__ unsigned int xfrag[2][MT * 2 * 256];   // 2 x 16 KB
    // z ring: 4 quarters x 32 t-rows
    __shared__ float zbuf[4 * TCH * TSTR];            // 43 KB
    // one-shot flags per period (monotone; no reset)
    __shared__ int zready[NCHK], zdone[NCHK], xdone[NCHK], xready2[NCHK], xready3[NCHK];

    const int tid = threadIdx.x;
    const int wv  = tid >> 6;
    const int ln  = tid & 63;
    const int b0  = blockIdx.x * BPB;

    if (tid < NCHK) {
        zready[tid] = 0; zdone[tid] = 0; xdone[tid] = 0;
        xready2[tid] = 0; xready3[tid] = 0;
    }

    // ---- gate mapping: MFMA col n = Keras gate col (q*3+m), q=n/3, m=n%3 ----
    const int n  = ln & 15;                 // 12 real gates + 4 pad
    const int q  = n / 3;                   // 0:i 1:f 2:g 3:o (n<12)
    const float scq = (q == 2) ? (-2.0f * L2E) : (-L2E);

    // ---- B-fragments: W stationary in VGPRs (wv1 only uses them) ----
    short8 bfrag[2];
    #pragma unroll
    for (int kt = 0; kt < 2; ++kt) {
        short8 s;
        #pragma unroll
        for (int e = 0; e < 8; ++e) {
            const int hh = e >> 2, j = e & 3;
            const int kk = kt * 32 + hh * 16 + 4 * (ln >> 4) + j;   // f index
            const float w = (n < 12 && wv == 1) ? W[kk * 12 + n] * scq : 0.0f;
            s[e] = (short)f2bf(w);
        }
        bfrag[kt] = s;
    }
    const float bias_s = (n < 12) ? bias[n] * scq : 0.0f;

    // ---- scan constants (wv0): lane n = gate col; elem e16 = ln>>4 (0..3) ----
    const int e16 = ln >> 4;
    float u0 = 0.f, u1 = 0.f, u2 = 0.f, gA = 0.f, gB = 0.f;
    if (n < 12) {
        u0 = U[0 * 12 + n] * scq;
        u1 = U[1 * 12 + n] * scq;
        u2 = U[2 * 12 + n] * scq;
        if (q == 2) { gA = -4.0f * L2E; gB = 2.0f * L2E; }  // pre-scaled tanh
        else        { gA = 1.0f;        gB = 0.0f;       }  // sigmoid
    }
    float cs = 0.f, h0b = 0.f, h1b = 0.f, h2b = 0.f;

    auto comp = [&](float z4) {
        const float z  = fmaf(h0b, u0, fmaf(h1b, u1, fmaf(h2b, u2, z4)));
        const float r  = fast_rcp(1.0f + exp2h(z));      // ONE exp2+rcp for all gates
        const float gt = fmaf(gA, r, gB);                // sigmoid / pre-scaled tanh
        const float iV = dppmv<DPP_SHR6>(gt);
        const float fV = dppmv<DPP_SHR3>(gt);
        const float oV = dppmv<DPP_SHL3>(gt);
        cs = fmaf(fV, cs, iV * gt);                      // g-lanes: gt = -2*L2E*g
        const float th = fmaf(2.0f, fast_rcp(1.0f + exp2h(cs)), -1.0f);  // tanh(c)
        const float h  = oV * th;                        // h_m on lane 6+m
        h0b = dppmv<DPP_NB6>(h);
        h1b = dppmv<DPP_NB7>(h);
        h2b = dppmv<DPP_NB8>(h);
    };

    auto scan32 = [&](int p) {
        const float* zp = zbuf + (size_t)((p & 3) * TCH) * TSTR + e16 * ESTR + n;
        float pf[8];
        #pragma unroll
        for (int i = 0; i < 8; ++i) pf[i] = zp[i * TSTR];
        #pragma unroll
        for (int tt = 0; tt < TCH; ++tt) {               // static pf indices
            const float z4 = pf[tt & 7];
            if (tt + 8 < TCH) pf[tt & 7] = zp[(tt + 8) * TSTR];
            comp(z4);
        }
    };

    // ---- staging (wv2-3): issue-early global loads, convert+write bf16 A-frags ----
    float4 v[PPT];
    const int stid = tid - 128;             // 0..127 for wv2-3
    auto stage_issue = [&](int ck) {
        const int t0 = ck * TCH;
        #pragma unroll
        for (int i = 0; i < PPT; ++i) {
            const int piece = i * NSTG + stid;
            const int row = piece >> 4, g = piece & 15;  // row = b*32 + t
            v[i] = *reinterpret_cast<const float4*>(
                x + ((size_t)(b0 + (row >> 5)) * T_SZ + (t0 + (row & 31))) * F_SZ + (g << 2));
        }
    };
    auto stage_write = [&](int buf) {
        #pragma unroll
        for (int i = 0; i < PPT; ++i) {
            const int piece = i * NSTG + stid;
            const int row = piece >> 4, g = piece & 15;
            const int u_off = ((row >> 4) * 2 + (g >> 3)) * 256
                            + (((row & 15) | ((g & 3) << 4)) << 2) + ((g >> 2) & 1) * 2;
            uint2 pk;
            pk.x = (unsigned)f2bf(v[i].x) | ((unsigned)f2bf(v[i].y) << 16);
            pk.y = (unsigned)f2bf(v[i].z) | ((unsigned)f2bf(v[i].w) << 16);
            *reinterpret_cast<uint2*>(&xfrag[buf][u_off]) = pk;
        }
    };

    auto mfma_period = [&](int p) {
        const int buf  = p & 1;
        const int qoff = (p & 3) * TCH;
        #pragma unroll
        for (int mt = 0; mt < MT; ++mt) {
            f32x4 acc = { bias_s, bias_s, bias_s, bias_s };
            const short8 a0 = *reinterpret_cast<const short8*>(&xfrag[buf][(mt * 2 + 0) * 256 + (ln << 2)]);
            const short8 a1 = *reinterpret_cast<const short8*>(&xfrag[buf][(mt * 2 + 1) * 256 + (ln << 2)]);
            acc = __builtin_amdgcn_mfma_f32_16x16x32_bf16(a0, bfrag[0], acc, 0, 0, 0);
            acc = __builtin_amdgcn_mfma_f32_16x16x32_bf16(a1, bfrag[1], acc, 0, 0, 0);
            const int rbase = mt * 16 + 4 * (ln >> 4);
            #pragma unroll
            for (int r = 0; r < 4; ++r) {
                const int rr = rbase + r;                 // row = b*32 + t
                zbuf[(size_t)(qoff + (rr & 31)) * TSTR + (rr >> 5) * ESTR + n] = acc[r];
            }
        }
    };

    __syncthreads();   // flags initialized (only barrier in the kernel)

    if (wv == 0) {
        // ---- scan: free-runs 512 steps; one flag check per 32 steps ----
        __builtin_amdgcn_s_setprio(1);
        for (int p = 0; p < NCHK; ++p) {
            wait_flag(&zready[p]);
            scan32(p);
            set_flag(&zdone[p]);
        }
        __builtin_amdgcn_s_setprio(0);
        if (n == 0) {   // lanes 0,16,32,48: elems 0..3
            const float logit = bdp[0] + h0b * Wd[0] + h1b * Wd[1] + h2b * Wd[2];
            out[b0 + e16] = sigm_n(logit);
        }
    } else if (wv == 1) {
        // ---- MFMA: paces itself behind staging, ahead of scan (ring-4) ----
        for (int p = 0; p < NCHK; ++p) {
            wait_flag(&xready2[p]);
            wait_flag(&xready3[p]);
            if (p >= 4) wait_flag(&zdone[p - 4]);   // zbuf slot reuse
            mfma_period(p);
            set_flag(&zready[p]);
            xdone[p] = 1;                            // reads long complete (covered by set_flag's fence)
        }
    } else {
        // ---- staging: issue one period ahead; write gated by MFMA consumption ----
        volatile int* xr = (wv == 2) ? xready2 : xready3;
        stage_issue(0);
        stage_write(0);
        set_flag(&xr[0]);
        stage_issue(1);
        for (int w = 1; w < NCHK; ++w) {
            if (w >= 2) wait_flag(&xdone[w - 2]);   // xfrag slot reuse
            stage_write(w & 1);
            set_flag(&xr[w]);
            if (w + 1 < NCHK) stage_issue(w + 1);
        }
    }
}

extern "C" void kernel_launch(void* const* d_in, const int* in_sizes, int n_in,
                              void* d_out, int out_size, void* d_ws, size_t ws_size,
                              hipStream_t stream) {
    (void)in_sizes; (void)n_in; (void)out_size; (void)d_ws; (void)ws_size;
    const float* x  = (const float*)d_in[0];
    const float* W  = (const float*)d_in[1];
    const float* U  = (const float*)d_in[2];
    const float* b  = (const float*)d_in[3];
    const float* Wd = (const float*)d_in[4];
    const float* bd = (const float*)d_in[5];
    float* out = (float*)d_out;

    lstm_mfma<<<NBLK, NTHR, 0, stream>>>(x, W, U, b, Wd, bd, out);
}

// Round 21
// 53.522 us; speedup vs baseline: 1.6294x; 1.0593x over previous
//
#include <hip/hip_runtime.h>
#include <hip/hip_bf16.h>
#include <cstdint>

#define B_SZ 2048
#define T_SZ 512
#define F_SZ 64
#define BPB  4              // batch rows per block
#define TCH  32             // timesteps per period
#define NCHK (T_SZ / TCH)   // 16 periods
#define NBLK (B_SZ / BPB)   // 512 -> 2 blocks/CU
#define NTHR 256            // wv0 scan, wv1 MFMA, wv2-3 staging
#define ROWS (BPB * TCH)    // 128 rows (b,t) per period
#define MT   (ROWS / 16)    // 8 M-tiles
#define NPC  (ROWS * 16)    // 2048 float4 staging pieces per period
#define NSTG 128            // staging threads (wv2+wv3)
#define PPT  (NPC / NSTG)   // 16 pieces per staging thread
#define TSTR 84             // zbuf t-stride (floats)
#define ESTR 20             // zbuf b-elem stride (floats)

#define L2E 1.4426950408889634f

typedef __attribute__((ext_vector_type(8))) short short8;
typedef __attribute__((ext_vector_type(4))) float f32x4;

__device__ __forceinline__ float fast_rcp(float x) { return __builtin_amdgcn_rcpf(x); }
__device__ __forceinline__ float exp2h(float x)    { return __builtin_amdgcn_exp2f(x); }
__device__ __forceinline__ float sigm_s(float zs)  { return fast_rcp(1.0f + exp2h(zs)); }
__device__ __forceinline__ float sigm_n(float x)   { return sigm_s(x * (-L2E)); }

__device__ __forceinline__ unsigned short f2bf(float f) {
    __hip_bfloat16 h = (__hip_bfloat16)f;   // RNE
    return *reinterpret_cast<unsigned short*>(&h);
}

template<int CTRL>
__device__ __forceinline__ float dppmv(float v) {
    return __int_as_float(__builtin_amdgcn_mov_dpp(__float_as_int(v), CTRL, 0xF, 0xF, true));
}
// row_shr:N -> lane i reads lane i-N ; row_shl:N -> lane i reads lane i+N
#define DPP_SHR6 0x116   // i-gates: src lanes 0..2 -> dst 6..8
#define DPP_SHR3 0x113   // f-gates: src lanes 3..5 -> dst 6..8
#define DPP_SHL3 0x103   // o-gates: src lanes 9..11 -> dst 6..8
// row_newbcast:N (0x150+N): broadcast row-lane N to all 16 lanes (VALU DPP)
#define DPP_NB6  0x156
#define DPP_NB7  0x157
#define DPP_NB8  0x158

__global__ __launch_bounds__(NTHR) void lstm_mfma(const float* __restrict__ x,
                                                  const float* __restrict__ W,
                                                  const float* __restrict__ U,
                                                  const float* __restrict__ bias,
                                                  const float* __restrict__ Wd,
                                                  const float* __restrict__ bdp,
                                                  float* __restrict__ out) {
    // A-fragment-ordered x (bf16): per (Mtile,Ktile): 64 lanes x 16B
    __shared__ unsigned int xfrag[2][MT * 2 * 256];   // 2 x 16 KB
    // z double buffer + 4 pad rows per buffer (branchless scan prefetch overrun)
    __shared__ float zbuf[2][(TCH + 4) * TSTR];       // 2 x 12 KB

    const int tid = threadIdx.x;
    const int wv  = tid >> 6;
    const int ln  = tid & 63;
    const int b0  = blockIdx.x * BPB;

    // ---- gate mapping: MFMA col n = Keras gate col (q*3+m), q=n/3, m=n%3 ----
    const int n  = ln & 15;                 // 12 real gates + 4 pad
    const int q  = n / 3;                   // 0:i 1:f 2:g 3:o (n<12)
    const float scq = (q == 2) ? (-2.0f * L2E) : (-L2E);

    // ---- B-fragments: W stationary in VGPRs (wv1 only uses them) ----
    short8 bfrag[2];
    #pragma unroll
    for (int kt = 0; kt < 2; ++kt) {
        short8 s;
        #pragma unroll
        for (int e = 0; e < 8; ++e) {
            const int hh = e >> 2, j = e & 3;
            const int kk = kt * 32 + hh * 16 + 4 * (ln >> 4) + j;   // f index
            const float w = (n < 12 && wv == 1) ? W[kk * 12 + n] * scq : 0.0f;
            s[e] = (short)f2bf(w);
        }
        bfrag[kt] = s;
    }
    const float bias_s = (n < 12) ? bias[n] * scq : 0.0f;

    // ---- scan constants (wv0): lane n = gate col; elem e16 = ln>>4 (0..3) ----
    const int e16 = ln >> 4;
    float u0 = 0.f, u1 = 0.f, u2 = 0.f, gA = 0.f, gB = 0.f;
    if (n < 12) {
        u0 = U[0 * 12 + n] * scq;
        u1 = U[1 * 12 + n] * scq;
        u2 = U[2 * 12 + n] * scq;
        if (q == 2) { gA = -4.0f * L2E; gB = 2.0f * L2E; }  // pre-scaled tanh
        else        { gA = 1.0f;        gB = 0.0f;       }  // sigmoid
    }
    // state: cs = -2*L2E*c (g-lanes 6..8); h broadcasts h0b/h1b/h2b
    float cs = 0.f, h0b = 0.f, h1b = 0.f, h2b = 0.f;

    auto comp = [&](float z4) {
        const float z  = fmaf(h0b, u0, fmaf(h1b, u1, fmaf(h2b, u2, z4)));
        const float r  = fast_rcp(1.0f + exp2h(z));      // ONE exp2+rcp for all gates
        const float gt = fmaf(gA, r, gB);                // sigmoid / pre-scaled tanh
        const float iV = dppmv<DPP_SHR6>(gt);            // i -> g-lanes
        const float fV = dppmv<DPP_SHR3>(gt);            // f -> g-lanes
        const float oV = dppmv<DPP_SHL3>(gt);            // o -> g-lanes
        cs = fmaf(fV, cs, iV * gt);                      // g-lanes: gt = -2*L2E*g
        const float th = fmaf(2.0f, fast_rcp(1.0f + exp2h(cs)), -1.0f);  // tanh(c)
        const float h  = oV * th;                        // h_m on lane 6+m
        h0b = dppmv<DPP_NB6>(h);                         // VALU row-broadcasts
        h1b = dppmv<DPP_NB7>(h);
        h2b = dppmv<DPP_NB8>(h);
    };

    // ---- SINGLE-AXIS CHANGE: rolled scan loop (unroll 4), ~0.9 KB body vs 6.4 KB ----
    auto scan32 = [&](const float* zb) {
        const float* zp = zb + e16 * ESTR + n;
        float pf[4];
        #pragma unroll
        for (int i = 0; i < 4; ++i) pf[i] = zp[i * TSTR];
        __builtin_amdgcn_s_setprio(1);
        #pragma unroll 4
        for (int tt = 0; tt < TCH; ++tt) {               // tt&3 static within unroll-4
            const float z4 = pf[tt & 3];
            pf[tt & 3] = zp[(tt + 4) * TSTR];            // rows TCH..TCH+3 are pad
            comp(z4);
        }
        __builtin_amdgcn_s_setprio(0);
    };

    // ---- staging (wv2-3 only): issue-early global loads, convert+write bf16 A-frags ----
    float4 v[PPT];
    const int stid = tid - 128;             // 0..127 for wv2-3
    auto stage_issue = [&](int ck) {
        const int t0 = ck * TCH;
        #pragma unroll
        for (int i = 0; i < PPT; ++i) {
            const int piece = i * NSTG + stid;
            const int row = piece >> 4, g = piece & 15;
            v[i] = *reinterpret_cast<const float4*>(
                x + ((size_t)(b0 + (row >> 5)) * T_SZ + (t0 + (row & 31))) * F_SZ + (g << 2));
        }
    };
    auto stage_write = [&](int buf) {
        #pragma unroll
        for (int i = 0; i < PPT; ++i) {
            const int piece = i * NSTG + stid;
            const int row = piece >> 4, g = piece & 15;
            const int u_off = ((row >> 4) * 2 + (g >> 3)) * 256
                            + (((row & 15) | ((g & 3) << 4)) << 2) + ((g >> 2) & 1) * 2;
            uint2 pk;
            pk.x = (unsigned)f2bf(v[i].x) | ((unsigned)f2bf(v[i].y) << 16);
            pk.y = (unsigned)f2bf(v[i].z) | ((unsigned)f2bf(v[i].w) << 16);
            *reinterpret_cast<uint2*>(&xfrag[buf][u_off]) = pk;
        }
    };

    auto mfma_chunk = [&](int cur) {
        #pragma unroll
        for (int mt = 0; mt < MT; ++mt) {
            f32x4 acc = { bias_s, bias_s, bias_s, bias_s };
            const short8 a0 = *reinterpret_cast<const short8*>(&xfrag[cur][(mt * 2 + 0) * 256 + (ln << 2)]);
            const short8 a1 = *reinterpret_cast<const short8*>(&xfrag[cur][(mt * 2 + 1) * 256 + (ln << 2)]);
            acc = __builtin_amdgcn_mfma_f32_16x16x32_bf16(a0, bfrag[0], acc, 0, 0, 0);
            acc = __builtin_amdgcn_mfma_f32_16x16x32_bf16(a1, bfrag[1], acc, 0, 0, 0);
            const int rbase = mt * 16 + 4 * (ln >> 4);
            #pragma unroll
            for (int r = 0; r < 4; ++r) {
                const int rr = rbase + r;                 // row = b*32 + t
                zbuf[cur][(rr & 31) * TSTR + (rr >> 5) * ESTR + n] = acc[r];
            }
        }
    };

    // ---- prologue: staging waves fill period 0 ----
    if (wv >= 2) { stage_issue(0); stage_write(0); }
    __syncthreads();

    // ---- pipeline: staging(k+1) || mfma z(k) || scan(k-1), one barrier/period ----
    for (int k = 0; k < NCHK; ++k) {
        const int cur = k & 1;
        if (wv >= 2) {
            if (k + 1 < NCHK) { stage_issue(k + 1); stage_write(cur ^ 1); }
        } else if (wv == 1) {
            mfma_chunk(cur);
        } else if (k > 0) {
            scan32(zbuf[cur ^ 1]);
        }
        __syncthreads();
    }

    // ---- epilogue: scan last period + dense head ----
    if (wv == 0) {
        scan32(zbuf[(NCHK - 1) & 1]);
        if (n == 0) {   // lanes 0,16,32,48: elems 0..3
            const float logit = bdp[0] + h0b * Wd[0] + h1b * Wd[1] + h2b * Wd[2];
            out[b0 + e16] = sigm_n(logit);
        }
    }
}

extern "C" void kernel_launch(void* const* d_in, const int* in_sizes, int n_in,
                              void* d_out, int out_size, void* d_ws, size_t ws_size,
                              hipStream_t stream) {
    (void)in_sizes; (void)n_in; (void)out_size; (void)d_ws; (void)ws_size;
    const float* x  = (const float*)d_in[0];
    const float* W  = (const float*)d_in[1];
    const float* U  = (const float*)d_in[2];
    const float* b  = (const float*)d_in[3];
    const float* Wd = (const float*)d_in[4];
    const float* bd = (const float*)d_in[5];
    float* out = (float*)d_out;

    lstm_mfma<<<NBLK, NTHR, 0, stream>>>(x, W, U, b, Wd, bd, out);
}